// Round 6
// baseline (1284.475 us; speedup 1.0000x reference)
//
#include <hip/hip_runtime.h>
#include <hip/hip_bf16.h>
#include <stdint.h>

// ------------- edge_index storage detection: int64 (odd words all zero) vs int32 -------------
// flag=0 -> int64 storage; flag=1 -> int32 storage. (Rounds 2-5 evidence: int32 on this harness.)

__global__ __launch_bounds__(256) void k_detect(const unsigned int* __restrict__ w, int* __restrict__ flag){
  int t = threadIdx.x;
  unsigned int acc = 0;
  #pragma unroll
  for (int i=0;i<16;++i) acc |= w[2*(t*16+i)+1];
  #pragma unroll
  for (int o=32;o>=1;o>>=1) acc |= __shfl_xor(acc, o);
  if ((t&63)==0 && acc) atomicOr(flag, 1);
}

// ---------------- CSR build (range-guarded) ----------------

__global__ __launch_bounds__(256) void k_count(const unsigned int* __restrict__ w, const int* __restrict__ mode,
                                               int* __restrict__ deg, int E, int N){
  int e = blockIdx.x*256 + threadIdx.x;
  if (e >= E) return;
  int d = (*mode) ? (int)w[(size_t)E + e] : (int)w[2*((size_t)E + e)];
  if ((unsigned)d < (unsigned)N) atomicAdd(&deg[d], 1);
}

__global__ __launch_bounds__(256) void k_scan1(const int* __restrict__ deg, int* __restrict__ bsum, int n){
  int t = threadIdx.x, b = blockIdx.x;
  int i0 = b*1024 + t*4;
  int s = 0;
  #pragma unroll
  for (int i=0;i<4;++i){ int idx=i0+i; s += (idx<n)?deg[idx]:0; }
  #pragma unroll
  for (int o=32;o>=1;o>>=1) s += __shfl_xor(s, o);
  __shared__ int wsm[4];
  if ((t&63)==0) wsm[t>>6] = s;
  __syncthreads();
  if (t==0) bsum[b] = wsm[0]+wsm[1]+wsm[2]+wsm[3];
}

__global__ __launch_bounds__(128) void k_scan2(const int* __restrict__ bsum, int* __restrict__ bbase,
                                               int* __restrict__ offN, int nb){
  __shared__ int sv[128];
  int t = threadIdx.x;
  int v = (t<nb)? bsum[t] : 0;
  sv[t] = v; __syncthreads();
  for (int o=1;o<128;o<<=1){
    int xv = (t>=o)? sv[t-o] : 0;
    __syncthreads();
    sv[t] += xv;
    __syncthreads();
  }
  if (t<nb) bbase[t] = sv[t]-v;
  if (t==127) offN[0] = sv[127];
}

__global__ __launch_bounds__(256) void k_scan3(const int* __restrict__ deg, const int* __restrict__ bbase,
                                               int* __restrict__ offs, int* __restrict__ cur, int n){
  int t = threadIdx.x, b = blockIdx.x, lane = t&63, w = t>>6;
  int i0 = b*1024 + t*4;
  int v[4]; int tot=0;
  #pragma unroll
  for (int i=0;i<4;++i){ int idx=i0+i; v[i] = (idx<n)?deg[idx]:0; tot += v[i]; }
  int s = tot;
  #pragma unroll
  for (int o=1;o<64;o<<=1){ int xv = __shfl_up(s,o); if (lane>=o) s += xv; }
  __shared__ int wsm[4];
  if (lane==63) wsm[w] = s;
  __syncthreads();
  int base = bbase[b];
  for (int j=0;j<w;++j) base += wsm[j];
  int excl = base + s - tot;
  #pragma unroll
  for (int i=0;i<4;++i){
    int idx=i0+i;
    if (idx<n){ offs[idx]=excl; cur[idx]=excl; excl += v[i]; }
  }
}

__global__ __launch_bounds__(256) void k_fill(const unsigned int* __restrict__ w, const int* __restrict__ mode,
                                              int* __restrict__ cur, int* __restrict__ csr, int E, int N){
  int e = blockIdx.x*256 + threadIdx.x;
  if (e >= E) return;
  int s, d;
  if (*mode){ s = (int)w[e];           d = (int)w[(size_t)E + e]; }
  else      { s = (int)w[2*(size_t)e]; d = (int)w[2*((size_t)E + e)]; }
  if ((unsigned)d < (unsigned)N && (unsigned)s < (unsigned)N){
    int p = atomicAdd(&cur[d],1);
    if ((unsigned)p < (unsigned)E) csr[p] = s;
  }
}

// ------------- gather, F=64 f32: h = (1+eps)*x_i + sum_j x_j -------------

__global__ __launch_bounds__(256) void k_gather64(const float* __restrict__ x, const int* __restrict__ offs,
                                                  const int* __restrict__ csr, const float* __restrict__ epsp,
                                                  float* __restrict__ h, int n){
  int gt = blockIdx.x*256 + threadIdx.x;
  int node = gt >> 6, lane = gt & 63;
  if (node >= n) return;
  float acc = (1.0f + epsp[0]) * x[(size_t)node*64 + lane];
  int u0 = offs[node], u1 = offs[node+1];
  for (int u=u0; u<u1; ++u){
    int s = csr[u];
    acc += x[(size_t)s*64 + lane];
  }
  h[(size_t)node*64 + lane] = acc;
}

// ------------- gather, F=128 f32 (float2 per lane) -------------

__global__ __launch_bounds__(256) void k_gather128(const float2* __restrict__ x2, const int* __restrict__ offs,
                                                   const int* __restrict__ csr, const float* __restrict__ epsp,
                                                   float2* __restrict__ h2, int n){
  int gt = blockIdx.x*256 + threadIdx.x;
  int node = gt >> 6, lane = gt & 63;
  if (node >= n) return;
  float e1 = 1.0f + epsp[0];
  float2 v = x2[(size_t)node*64 + lane];
  float a0 = e1*v.x, a1 = e1*v.y;
  int u0 = offs[node], u1 = offs[node+1];
  for (int u=u0; u<u1; ++u){
    int s = csr[u];
    float2 u2 = x2[(size_t)s*64 + lane];
    a0 += u2.x; a1 += u2.y;
  }
  h2[(size_t)node*64 + lane] = make_float2(a0, a1);
}

// ------------- plain f32 matmul + bias + relu: Y[n][c] = relu(b[c] + sum_k X[n][k] W[k][c]) -------------

__global__ void k_mm(const float* __restrict__ X, const float* __restrict__ W,
                     const float* __restrict__ bias, float* __restrict__ Y,
                     int n, int K, int M){
  int c  = threadIdx.x;
  int n0 = blockIdx.x*4;
  const float* x0 = X + (size_t)n0*K;
  float a0=0.f, a1=0.f, a2=0.f, a3=0.f;
  #pragma unroll 8
  for (int k=0;k<K;++k){
    float wv = W[(size_t)k*M + c];
    a0 = fmaf(x0[k],       wv, a0);
    a1 = fmaf(x0[K+k],     wv, a1);
    a2 = fmaf(x0[2*K+k],   wv, a2);
    a3 = fmaf(x0[3*K+k],   wv, a3);
  }
  float b = bias[c];
  a0 = fmaxf(a0+b, 0.f); a1 = fmaxf(a1+b, 0.f);
  a2 = fmaxf(a2+b, 0.f); a3 = fmaxf(a3+b, 0.f);
  if (n0   < n) Y[(size_t)n0*M     + c] = a0;
  if (n0+1 < n) Y[(size_t)(n0+1)*M + c] = a1;
  if (n0+2 < n) Y[(size_t)(n0+2)*M + c] = a2;
  if (n0+3 < n) Y[(size_t)(n0+3)*M + c] = a3;
}

// ------------- emb writeback (f32 -> f32: output dtype is float32) -------------

__global__ __launch_bounds__(256) void k_emb(const float* __restrict__ x3, float* __restrict__ emb, int n){
  int gt = blockIdx.x*256 + threadIdx.x;
  int node = gt >> 6, lane = gt & 63;
  if (node >= n) return;
  emb[(size_t)node*64 + lane] = x3[(size_t)node*64 + lane];
}

// ------------- final FC: out[n][j] = bfc[j] + sum_k x3[n][k] Wfc[k][j] (no relu), f32 out -------------

__global__ __launch_bounds__(256) void k_fc(const float* __restrict__ x3, const float* __restrict__ Wfc,
                                            const float* __restrict__ bfc, float* __restrict__ outp, int n){
  int t = threadIdx.x;
  int node = blockIdx.x*32 + (t>>3);
  int j = t&7;
  if (node >= n) return;
  float acc = bfc[j];
  const float* xr = x3 + (size_t)node*64;
  #pragma unroll 8
  for (int k=0;k<64;++k) acc = fmaf(xr[k], Wfc[k*8+j], acc);
  outp[(size_t)node*8 + j] = acc;
}

// ---------------- launcher ----------------

extern "C" void kernel_launch(void* const* d_in, const int* in_sizes, int n_in,
                              void* d_out, int out_size, void* d_ws, size_t ws_size,
                              hipStream_t stream)
{
  const int N = in_sizes[0] / 64;
  const int E = in_sizes[1] / 2;
  const float*        x    = (const float*)d_in[0];
  const unsigned int* ew   = (const unsigned int*)d_in[1];
  const float* eps1 = (const float*)d_in[2];
  const float* eps2 = (const float*)d_in[3];
  const float* eps3 = (const float*)d_in[4];
  const float* W1a  = (const float*)d_in[5];
  const float* b1a  = (const float*)d_in[6];
  const float* W1b  = (const float*)d_in[7];
  const float* b1b  = (const float*)d_in[8];
  const float* W2a  = (const float*)d_in[9];
  const float* b2a  = (const float*)d_in[10];
  const float* W2b  = (const float*)d_in[11];
  const float* b2b  = (const float*)d_in[12];
  const float* W3a  = (const float*)d_in[13];
  const float* b3a  = (const float*)d_in[14];
  const float* W3b  = (const float*)d_in[15];
  const float* b3b  = (const float*)d_in[16];
  const float* Wfc  = (const float*)d_in[17];
  const float* bfc  = (const float*)d_in[18];

  float* outp = (float*)d_out;                 // output dtype = float32 (reference dtype)
  float* emb  = outp + (size_t)N*8;

  const int Npad = ((N + 63)/64)*64;
  const int nb   = (N + 1023)/1024;

  char* ws = (char*)d_ws;
  size_t o = 0;
  auto alloc = [&](size_t bytes)->char* {
    char* p = ws + o;
    o = (o + bytes + 255) & ~(size_t)255;
    return p;
  };
  int*   mode  = (int*)alloc(4);
  int*   deg   = (int*)alloc((size_t)N*4);
  int*   cur   = (int*)alloc((size_t)N*4);
  int*   offs  = (int*)alloc((size_t)(N+1)*4);
  int*   bsum  = (int*)alloc((size_t)nb*4);
  int*   bbase = (int*)alloc((size_t)nb*4);
  int*   csr   = (int*)alloc((size_t)E*4);
  float* A     = (float*)alloc((size_t)Npad*128*4);
  float* B     = (float*)alloc((size_t)Npad*128*4);
  float* C     = (float*)alloc((size_t)Npad*128*4);

  hipMemsetAsync(mode, 0, 4, stream);
  hipMemsetAsync(deg, 0, (size_t)N*4, stream);
  k_detect<<<1, 256, 0, stream>>>(ew, mode);
  k_count<<<(E+255)/256, 256, 0, stream>>>(ew, mode, deg, E, N);
  k_scan1<<<nb, 256, 0, stream>>>(deg, bsum, N);
  k_scan2<<<1, 128, 0, stream>>>(bsum, bbase, offs + N, nb);
  k_scan3<<<nb, 256, 0, stream>>>(deg, bbase, offs, cur, N);
  k_fill<<<(E+255)/256, 256, 0, stream>>>(ew, mode, cur, csr, E, N);

  // layer 1: x (N x 64) -> A -> B -> C (N x 128)
  k_gather64<<<(N+3)/4, 256, 0, stream>>>(x, offs, csr, eps1, A, N);
  k_mm<<<Npad/4, 128, 0, stream>>>(A, W1a, b1a, B, N, 64, 128);
  k_mm<<<Npad/4, 128, 0, stream>>>(B, W1b, b1b, C, N, 128, 128);
  // layer 2: C -> A -> B -> C (N x 128)
  k_gather128<<<(N+3)/4, 256, 0, stream>>>((const float2*)C, offs, csr, eps2, (float2*)A, N);
  k_mm<<<Npad/4, 128, 0, stream>>>(A, W2a, b2a, B, N, 128, 128);
  k_mm<<<Npad/4, 128, 0, stream>>>(B, W2b, b2b, C, N, 128, 128);
  // layer 3: C -> A -> B -> C (N x 64)
  k_gather128<<<(N+3)/4, 256, 0, stream>>>((const float2*)C, offs, csr, eps3, (float2*)A, N);
  k_mm<<<Npad/4, 64, 0, stream>>>(A, W3a, b3a, B, N, 128, 64);
  k_mm<<<Npad/4, 64, 0, stream>>>(B, W3b, b3b, C, N, 64, 64);
  // outputs (f32)
  k_emb<<<(N+3)/4, 256, 0, stream>>>(C, emb, N);
  k_fc<<<(N+31)/32, 256, 0, stream>>>(C, Wfc, bfc, outp, N);
}

// Round 8
// 596.920 us; speedup vs baseline: 2.1518x; 2.1518x over previous
//
#include <hip/hip_runtime.h>
#include <hip/hip_bf16.h>
#include <stdint.h>

typedef unsigned short ushort_t;
typedef __attribute__((ext_vector_type(8))) short short8;
typedef __attribute__((ext_vector_type(4))) float floatx4;

__device__ __forceinline__ float bf2f(unsigned short u){
  union { unsigned int i; float f; } v; v.i = ((unsigned int)u) << 16; return v.f;
}
__device__ __forceinline__ unsigned short f2bf(float f){
  union { float f; unsigned int i; } v; v.f = f;
  unsigned int r = v.i + 0x7FFFu + ((v.i >> 16) & 1u);
  return (unsigned short)(r >> 16);
}
__device__ __forceinline__ unsigned int pack2(unsigned short lo, unsigned short hi){
  return ((unsigned int)hi << 16) | (unsigned int)lo;
}

// ------------- edge_index storage detection (int32 words on this harness; probe kept for safety) -------------

__global__ __launch_bounds__(256) void k_detect(const unsigned int* __restrict__ w, int* __restrict__ flag){
  int t = threadIdx.x;
  unsigned int acc = 0;
  #pragma unroll
  for (int i=0;i<16;++i) acc |= w[2*(t*16+i)+1];
  #pragma unroll
  for (int o=32;o>=1;o>>=1) acc |= __shfl_xor(acc, o);
  if ((t&63)==0 && acc) atomicOr(flag, 1);
}

// ---------------- CSR build (range-guarded) ----------------

__global__ __launch_bounds__(256) void k_count(const unsigned int* __restrict__ w, const int* __restrict__ mode,
                                               int* __restrict__ deg, int E, int N){
  int e = blockIdx.x*256 + threadIdx.x;
  if (e >= E) return;
  int d = (*mode) ? (int)w[(size_t)E + e] : (int)w[2*((size_t)E + e)];
  if ((unsigned)d < (unsigned)N) atomicAdd(&deg[d], 1);
}

__global__ __launch_bounds__(256) void k_scan1(const int* __restrict__ deg, int* __restrict__ bsum, int n){
  int t = threadIdx.x, b = blockIdx.x;
  int i0 = b*1024 + t*4;
  int s = 0;
  #pragma unroll
  for (int i=0;i<4;++i){ int idx=i0+i; s += (idx<n)?deg[idx]:0; }
  #pragma unroll
  for (int o=32;o>=1;o>>=1) s += __shfl_xor(s, o);
  __shared__ int wsm[4];
  if ((t&63)==0) wsm[t>>6] = s;
  __syncthreads();
  if (t==0) bsum[b] = wsm[0]+wsm[1]+wsm[2]+wsm[3];
}

__global__ __launch_bounds__(128) void k_scan2(const int* __restrict__ bsum, int* __restrict__ bbase,
                                               int* __restrict__ offN, int nb){
  __shared__ int sv[128];
  int t = threadIdx.x;
  int v = (t<nb)? bsum[t] : 0;
  sv[t] = v; __syncthreads();
  for (int o=1;o<128;o<<=1){
    int xv = (t>=o)? sv[t-o] : 0;
    __syncthreads();
    sv[t] += xv;
    __syncthreads();
  }
  if (t<nb) bbase[t] = sv[t]-v;
  if (t==127) offN[0] = sv[127];
}

__global__ __launch_bounds__(256) void k_scan3(const int* __restrict__ deg, const int* __restrict__ bbase,
                                               int* __restrict__ offs, int* __restrict__ cur, int n){
  int t = threadIdx.x, b = blockIdx.x, lane = t&63, w = t>>6;
  int i0 = b*1024 + t*4;
  int v[4]; int tot=0;
  #pragma unroll
  for (int i=0;i<4;++i){ int idx=i0+i; v[i] = (idx<n)?deg[idx]:0; tot += v[i]; }
  int s = tot;
  #pragma unroll
  for (int o=1;o<64;o<<=1){ int xv = __shfl_up(s,o); if (lane>=o) s += xv; }
  __shared__ int wsm[4];
  if (lane==63) wsm[w] = s;
  __syncthreads();
  int base = bbase[b];
  for (int j=0;j<w;++j) base += wsm[j];
  int excl = base + s - tot;
  #pragma unroll
  for (int i=0;i<4;++i){
    int idx=i0+i;
    if (idx<n){ offs[idx]=excl; cur[idx]=excl; excl += v[i]; }
  }
}

__global__ __launch_bounds__(256) void k_fill(const unsigned int* __restrict__ w, const int* __restrict__ mode,
                                              int* __restrict__ cur, int* __restrict__ csr, int E, int N){
  int e = blockIdx.x*256 + threadIdx.x;
  if (e >= E) return;
  int s, d;
  if (*mode){ s = (int)w[e];           d = (int)w[(size_t)E + e]; }
  else      { s = (int)w[2*(size_t)e]; d = (int)w[2*((size_t)E + e)]; }
  if ((unsigned)d < (unsigned)N && (unsigned)s < (unsigned)N){
    int p = atomicAdd(&cur[d],1);
    if ((unsigned)p < (unsigned)E) csr[p] = s;
  }
}

// ------------- weight permutation: f32 row-major -> bf16 MFMA-B layout -------------
// element (k,n) -> block (nt=n>>4)*(K/32)+(k>>5), offset ((k>>3)&3)*128 + (n&15)*8 + (k&7)

__global__ __launch_bounds__(256) void k_perm(const float* W1a, const float* W1b, const float* W2a,
                                              const float* W2b, const float* W3a, const float* W3b,
                                              const float* Wfc, ushort_t* out){
  int id = blockIdx.x*256 + threadIdx.x;
  const float* src; int K, M, base, local;
  if      (id <  8192){ src=W1a; K=64;  M=128; base=0;     local=id; }
  else if (id < 24576){ src=W1b; K=128; M=128; base=8192;  local=id-8192; }
  else if (id < 40960){ src=W2a; K=128; M=128; base=24576; local=id-24576; }
  else if (id < 57344){ src=W2b; K=128; M=128; base=40960; local=id-40960; }
  else if (id < 65536){ src=W3a; K=128; M=64;  base=57344; local=id-57344; }
  else if (id < 69632){ src=W3b; K=64;  M=64;  base=65536; local=id-65536; }
  else if (id < 70656){ src=Wfc; K=64;  M=16;  base=69632; local=id-69632; }
  else return;
  int k = local / M, nn = local - k*M;
  float val;
  if (src == Wfc) val = (nn<8) ? Wfc[k*8+nn] : 0.0f;
  else            val = src[k*M+nn];
  int idx = (((nn>>4)*(K/32) + (k>>5))*4 + ((k>>3)&3))*128 + (nn&15)*8 + (k&7);
  out[base+idx] = f2bf(val);
}

// ------------- gather L1: f32 x -> bf16 h ; unrolled x4 for latency hiding -------------

__global__ __launch_bounds__(256) void k_gather64(const float* __restrict__ x, const int* __restrict__ offs,
                                                  const int* __restrict__ csr, const float* __restrict__ epsp,
                                                  ushort_t* __restrict__ h, int n){
  int gt = blockIdx.x*256 + threadIdx.x;
  int node = gt >> 6, lane = gt & 63;
  if (node >= n) return;
  float acc = (1.0f + epsp[0]) * x[(size_t)node*64 + lane];
  int u0 = offs[node], u1 = offs[node+1];
  int u = u0;
  float e0=0.f, e1=0.f, e2=0.f, e3=0.f;
  for (; u+3 < u1; u += 4){
    int s0 = csr[u], s1 = csr[u+1], s2 = csr[u+2], s3 = csr[u+3];
    e0 += x[(size_t)s0*64 + lane];
    e1 += x[(size_t)s1*64 + lane];
    e2 += x[(size_t)s2*64 + lane];
    e3 += x[(size_t)s3*64 + lane];
  }
  for (; u < u1; ++u) acc += x[(size_t)csr[u]*64 + lane];
  acc += (e0+e1) + (e2+e3);
  h[(size_t)node*64 + lane] = f2bf(acc);
}

// ------------- gather L2/L3: bf16 (uint pairs), F=128, unrolled x4 -------------

__global__ __launch_bounds__(256) void k_gather_bf(const unsigned int* __restrict__ x2, const int* __restrict__ offs,
                                                   const int* __restrict__ csr, const float* __restrict__ epsp,
                                                   unsigned int* __restrict__ h2, int n){
  int gt = blockIdx.x*256 + threadIdx.x;
  int node = gt >> 6, lane = gt & 63;
  if (node >= n) return;
  float e1s = 1.0f + epsp[0];
  unsigned int xv = x2[(size_t)node*64 + lane];
  float a0 = e1s*bf2f((unsigned short)(xv & 0xffffu));
  float a1 = e1s*bf2f((unsigned short)(xv >> 16));
  int u0 = offs[node], u1 = offs[node+1];
  int u = u0;
  for (; u+3 < u1; u += 4){
    int s0 = csr[u], s1 = csr[u+1], s2 = csr[u+2], s3 = csr[u+3];
    unsigned int v0 = x2[(size_t)s0*64 + lane];
    unsigned int v1 = x2[(size_t)s1*64 + lane];
    unsigned int v2 = x2[(size_t)s2*64 + lane];
    unsigned int v3 = x2[(size_t)s3*64 + lane];
    a0 += bf2f((unsigned short)(v0 & 0xffffu)) + bf2f((unsigned short)(v1 & 0xffffu))
        + bf2f((unsigned short)(v2 & 0xffffu)) + bf2f((unsigned short)(v3 & 0xffffu));
    a1 += bf2f((unsigned short)(v0 >> 16)) + bf2f((unsigned short)(v1 >> 16))
        + bf2f((unsigned short)(v2 >> 16)) + bf2f((unsigned short)(v3 >> 16));
  }
  for (; u < u1; ++u){
    unsigned int v = x2[(size_t)csr[u]*64 + lane];
    a0 += bf2f((unsigned short)(v & 0xffffu));
    a1 += bf2f((unsigned short)(v >> 16));
  }
  h2[(size_t)node*64 + lane] = pack2(f2bf(a0), f2bf(a1));
}

// ---------------- fused MFMA MLP: x_next = relu(relu(h@Wa+ba)@Wb+bb); LAST adds emb(f32)+FC(f32) ----------------
// A-frag (m=lane&15, k=quad*8+j) from row-major bf16 h (16B/lane).
// B-frag from permuted weights (contiguous 16B/lane). D: col=lane&15, row=quad*4+reg.

template<int F, int M1, int M2, bool LAST>
__global__ __launch_bounds__(256)
void k_mlp(const ushort_t* __restrict__ h,
           const ushort_t* __restrict__ wp1, const float* __restrict__ b1,
           const ushort_t* __restrict__ wp2, const float* __restrict__ b2,
           ushort_t* __restrict__ xout,      // !LAST: bf16 next-layer x
           float* __restrict__ embp,         // LAST: f32 emb
           const ushort_t* __restrict__ wpfc, const float* __restrict__ bfc,
           float* __restrict__ outp, int n)
{
  constexpr int NT1 = M1/16, NT2 = M2/16, KC1 = F/32, KC2 = M1/32;
  __shared__ short sC1[4*(M1/8)*136];
  __shared__ short sX3[LAST ? (4*8*136) : 1];
  int tid = threadIdx.x, lane = tid&63, w = tid>>6;
  int m16 = lane&15, quad = lane>>4;
  int row0 = blockIdx.x*64 + w*16;
  size_t arow = (size_t)(row0 + m16);

  // stage B: C1 = relu(h @ Wa + ba)
  floatx4 acc[NT1];
  #pragma unroll
  for (int i=0;i<NT1;++i) acc[i] = (floatx4){0.f,0.f,0.f,0.f};
  #pragma unroll
  for (int kc=0; kc<KC1; ++kc){
    short8 a = *(const short8*)(h + arow*F + kc*32 + quad*8);
    #pragma unroll
    for (int nt=0; nt<NT1; ++nt){
      short8 b = *(const short8*)(wp1 + (size_t)((nt*KC1+kc)*64 + lane)*8);
      acc[nt] = __builtin_amdgcn_mfma_f32_16x16x32_bf16(a, b, acc[nt], 0, 0, 0);
    }
  }
  #pragma unroll
  for (int nt=0; nt<NT1; ++nt){
    int c = nt*16 + m16;
    float bias = b1[c];
    #pragma unroll
    for (int r=0;r<4;++r){
      float v = fmaxf(acc[nt][r] + bias, 0.f);
      int mm = quad*4 + r;
      sC1[(w*(M1/8) + (c>>3))*136 + mm*8 + (c&7)] = (short)f2bf(v);
    }
  }
  __syncthreads();

  // stage C: X = relu(C1 @ Wb + bb)
  floatx4 acc2[NT2];
  #pragma unroll
  for (int i=0;i<NT2;++i) acc2[i] = (floatx4){0.f,0.f,0.f,0.f};
  #pragma unroll
  for (int kc=0; kc<KC2; ++kc){
    short8 a = *(const short8*)&sC1[(w*(M1/8) + kc*4 + quad)*136 + m16*8];
    #pragma unroll
    for (int nt=0; nt<NT2; ++nt){
      short8 b = *(const short8*)(wp2 + (size_t)((nt*KC2+kc)*64 + lane)*8);
      acc2[nt] = __builtin_amdgcn_mfma_f32_16x16x32_bf16(a, b, acc2[nt], 0, 0, 0);
    }
  }
  #pragma unroll
  for (int nt=0; nt<NT2; ++nt){
    int c = nt*16 + m16;
    float bias = b2[c];
    #pragma unroll
    for (int r=0;r<4;++r){
      float v = fmaxf(acc2[nt][r] + bias, 0.f);
      int mm = quad*4 + r;
      int row = row0 + mm;
      if constexpr (!LAST){
        if (row < n) xout[(size_t)row*M2 + c] = f2bf(v);
      } else {
        if (row < n) embp[(size_t)row*64 + c] = v;                // f32 emb
        sX3[(w*8 + (c>>3))*136 + mm*8 + (c&7)] = (short)f2bf(v);
      }
    }
  }

  if constexpr (LAST){
    __syncthreads();
    floatx4 accf = (floatx4){0.f,0.f,0.f,0.f};
    #pragma unroll
    for (int kc=0; kc<2; ++kc){
      short8 a = *(const short8*)&sX3[(w*8 + kc*4 + quad)*136 + m16*8];
      short8 b = *(const short8*)(wpfc + (size_t)(kc*64 + lane)*8);
      accf = __builtin_amdgcn_mfma_f32_16x16x32_bf16(a, b, accf, 0, 0, 0);
    }
    if (m16 < 8){
      float bias = bfc[m16];
      #pragma unroll
      for (int r=0;r<4;++r){
        int row = row0 + quad*4 + r;
        if (row < n) outp[(size_t)row*8 + m16] = accf[r] + bias;  // f32 out
      }
    }
  }
}

// ---------------- launcher ----------------

extern "C" void kernel_launch(void* const* d_in, const int* in_sizes, int n_in,
                              void* d_out, int out_size, void* d_ws, size_t ws_size,
                              hipStream_t stream)
{
  const int N = in_sizes[0] / 64;
  const int E = in_sizes[1] / 2;
  const float*        x    = (const float*)d_in[0];
  const unsigned int* ew   = (const unsigned int*)d_in[1];
  const float* eps1 = (const float*)d_in[2];
  const float* eps2 = (const float*)d_in[3];
  const float* eps3 = (const float*)d_in[4];
  const float* W1a  = (const float*)d_in[5];
  const float* b1a  = (const float*)d_in[6];
  const float* W1b  = (const float*)d_in[7];
  const float* b1b  = (const float*)d_in[8];
  const float* W2a  = (const float*)d_in[9];
  const float* b2a  = (const float*)d_in[10];
  const float* W2b  = (const float*)d_in[11];
  const float* b2b  = (const float*)d_in[12];
  const float* W3a  = (const float*)d_in[13];
  const float* b3a  = (const float*)d_in[14];
  const float* W3b  = (const float*)d_in[15];
  const float* b3b  = (const float*)d_in[16];
  const float* Wfc  = (const float*)d_in[17];
  const float* bfc  = (const float*)d_in[18];

  float* outp = (float*)d_out;                 // f32 output (verified round 6)
  float* emb  = outp + (size_t)N*8;

  const int Npad = ((N + 63)/64)*64;
  const int nb   = (N + 1023)/1024;

  char* ws = (char*)d_ws;
  size_t o = 0;
  auto alloc = [&](size_t bytes)->char* {
    char* p = ws + o;
    o = (o + bytes + 255) & ~(size_t)255;
    return p;
  };
  int*      mode  = (int*)alloc(4);
  int*      deg   = (int*)alloc((size_t)N*4);
  int*      cur   = (int*)alloc((size_t)N*4);
  int*      offs  = (int*)alloc((size_t)(N+1)*4);
  int*      bsum  = (int*)alloc((size_t)nb*4);
  int*      bbase = (int*)alloc((size_t)nb*4);
  int*      csr   = (int*)alloc((size_t)E*4);
  ushort_t* wperm = (ushort_t*)alloc(70656ull*2);
  ushort_t* hbuf  = (ushort_t*)alloc((size_t)Npad*128*2);   // gather output (bf16)
  ushort_t* x1    = (ushort_t*)alloc((size_t)Npad*128*2);   // layer outputs (bf16)

  hipMemsetAsync(mode, 0, 4, stream);
  hipMemsetAsync(deg, 0, (size_t)N*4, stream);
  k_detect<<<1, 256, 0, stream>>>(ew, mode);
  k_count<<<(E+255)/256, 256, 0, stream>>>(ew, mode, deg, E, N);
  k_scan1<<<nb, 256, 0, stream>>>(deg, bsum, N);
  k_scan2<<<1, 128, 0, stream>>>(bsum, bbase, offs + N, nb);
  k_scan3<<<nb, 256, 0, stream>>>(deg, bbase, offs, cur, N);
  k_fill<<<(E+255)/256, 256, 0, stream>>>(ew, mode, cur, csr, E, N);
  k_perm<<<(70656+255)/256, 256, 0, stream>>>(W1a, W1b, W2a, W2b, W3a, W3b, Wfc, wperm);

  // layer 1 (64 -> 128)
  k_gather64<<<(N+3)/4, 256, 0, stream>>>(x, offs, csr, eps1, hbuf, N);
  k_mlp<64,128,128,false><<<Npad/64, 256, 0, stream>>>(hbuf, wperm+0, b1a, wperm+8192, b1b,
                                                       x1, nullptr, nullptr, nullptr, nullptr, N);
  // layer 2 (128 -> 128)
  k_gather_bf<<<(N+3)/4, 256, 0, stream>>>((const unsigned int*)x1, offs, csr, eps2,
                                           (unsigned int*)hbuf, N);
  k_mlp<128,128,128,false><<<Npad/64, 256, 0, stream>>>(hbuf, wperm+24576, b2a, wperm+40960, b2b,
                                                        x1, nullptr, nullptr, nullptr, nullptr, N);
  // layer 3 (128 -> 64) + FC (64 -> 8)
  k_gather_bf<<<(N+3)/4, 256, 0, stream>>>((const unsigned int*)x1, offs, csr, eps3,
                                           (unsigned int*)hbuf, N);
  k_mlp<128,64,64,true><<<Npad/64, 256, 0, stream>>>(hbuf, wperm+57344, b3a, wperm+65536, b3b,
                                                     nullptr, emb, wperm+69632, bfc, outp, N);
}

// Round 9
// 582.862 us; speedup vs baseline: 2.2037x; 1.0241x over previous
//
#include <hip/hip_runtime.h>
#include <hip/hip_bf16.h>
#include <stdint.h>

typedef unsigned short ushort_t;
typedef __attribute__((ext_vector_type(8))) short short8;
typedef __attribute__((ext_vector_type(4))) float floatx4;

__device__ __forceinline__ float bf2f(unsigned short u){
  union { unsigned int i; float f; } v; v.i = ((unsigned int)u) << 16; return v.f;
}
__device__ __forceinline__ unsigned short f2bf(float f){
  union { float f; unsigned int i; } v; v.f = f;
  unsigned int r = v.i + 0x7FFFu + ((v.i >> 16) & 1u);
  return (unsigned short)(r >> 16);
}
__device__ __forceinline__ unsigned int pack2(unsigned short lo, unsigned short hi){
  return ((unsigned int)hi << 16) | (unsigned int)lo;
}

// ------------- edge_index storage detection (int32 words on this harness; probe kept for safety) -------------

__global__ __launch_bounds__(256) void k_detect(const unsigned int* __restrict__ w, int* __restrict__ flag){
  int t = threadIdx.x;
  unsigned int acc = 0;
  #pragma unroll
  for (int i=0;i<16;++i) acc |= w[2*(t*16+i)+1];
  #pragma unroll
  for (int o=32;o>=1;o>>=1) acc |= __shfl_xor(acc, o);
  if ((t&63)==0 && acc) atomicOr(flag, 1);
}

// ---------------- CSR build (range-guarded), ILP x4 ----------------

__global__ __launch_bounds__(256) void k_count(const unsigned int* __restrict__ w, const int* __restrict__ mode,
                                               int* __restrict__ deg, int E, int N){
  int base = blockIdx.x*1024 + threadIdx.x;
  int m = *mode;
  int d[4];
  #pragma unroll
  for (int i=0;i<4;++i){
    int e = base + i*256;
    d[i] = -1;
    if (e < E) d[i] = m ? (int)w[(size_t)E + e] : (int)w[2*((size_t)E + e)];
  }
  #pragma unroll
  for (int i=0;i<4;++i)
    if ((unsigned)d[i] < (unsigned)N) atomicAdd(&deg[d[i]], 1);
}

__global__ __launch_bounds__(256) void k_scan1(const int* __restrict__ deg, int* __restrict__ bsum, int n){
  int t = threadIdx.x, b = blockIdx.x;
  int i0 = b*1024 + t*4;
  int s = 0;
  #pragma unroll
  for (int i=0;i<4;++i){ int idx=i0+i; s += (idx<n)?deg[idx]:0; }
  #pragma unroll
  for (int o=32;o>=1;o>>=1) s += __shfl_xor(s, o);
  __shared__ int wsm[4];
  if ((t&63)==0) wsm[t>>6] = s;
  __syncthreads();
  if (t==0) bsum[b] = wsm[0]+wsm[1]+wsm[2]+wsm[3];
}

__global__ __launch_bounds__(128) void k_scan2(const int* __restrict__ bsum, int* __restrict__ bbase,
                                               int* __restrict__ offN, int nb){
  __shared__ int sv[128];
  int t = threadIdx.x;
  int v = (t<nb)? bsum[t] : 0;
  sv[t] = v; __syncthreads();
  for (int o=1;o<128;o<<=1){
    int xv = (t>=o)? sv[t-o] : 0;
    __syncthreads();
    sv[t] += xv;
    __syncthreads();
  }
  if (t<nb) bbase[t] = sv[t]-v;
  if (t==127) offN[0] = sv[127];
}

__global__ __launch_bounds__(256) void k_scan3(const int* __restrict__ deg, const int* __restrict__ bbase,
                                               int* __restrict__ offs, int* __restrict__ cur, int n){
  int t = threadIdx.x, b = blockIdx.x, lane = t&63, w = t>>6;
  int i0 = b*1024 + t*4;
  int v[4]; int tot=0;
  #pragma unroll
  for (int i=0;i<4;++i){ int idx=i0+i; v[i] = (idx<n)?deg[idx]:0; tot += v[i]; }
  int s = tot;
  #pragma unroll
  for (int o=1;o<64;o<<=1){ int xv = __shfl_up(s,o); if (lane>=o) s += xv; }
  __shared__ int wsm[4];
  if (lane==63) wsm[w] = s;
  __syncthreads();
  int base = bbase[b];
  for (int j=0;j<w;++j) base += wsm[j];
  int excl = base + s - tot;
  #pragma unroll
  for (int i=0;i<4;++i){
    int idx=i0+i;
    if (idx<n){ offs[idx]=excl; cur[idx]=excl; excl += v[i]; }
  }
}

__global__ __launch_bounds__(256) void k_fill(const unsigned int* __restrict__ w, const int* __restrict__ mode,
                                              int* __restrict__ cur, int* __restrict__ csr, int E, int N){
  int base = blockIdx.x*1024 + threadIdx.x;
  int m = *mode;
  int s[4], d[4];
  #pragma unroll
  for (int i=0;i<4;++i){
    int e = base + i*256;
    d[i] = -1; s[i] = 0;
    if (e < E){
      if (m){ s[i] = (int)w[e];           d[i] = (int)w[(size_t)E + e]; }
      else  { s[i] = (int)w[2*(size_t)e]; d[i] = (int)w[2*((size_t)E + e)]; }
    }
  }
  int p[4];
  #pragma unroll
  for (int i=0;i<4;++i){
    p[i] = -1;
    if ((unsigned)d[i] < (unsigned)N && (unsigned)s[i] < (unsigned)N)
      p[i] = atomicAdd(&cur[d[i]], 1);
  }
  #pragma unroll
  for (int i=0;i<4;++i)
    if ((unsigned)p[i] < (unsigned)E) csr[p[i]] = s[i];
}

// ------------- weight permutation: f32 row-major -> bf16 MFMA-B layout -------------

__global__ __launch_bounds__(256) void k_perm(const float* W1a, const float* W1b, const float* W2a,
                                              const float* W2b, const float* W3a, const float* W3b,
                                              const float* Wfc, ushort_t* out){
  int id = blockIdx.x*256 + threadIdx.x;
  const float* src; int K, M, base, local;
  if      (id <  8192){ src=W1a; K=64;  M=128; base=0;     local=id; }
  else if (id < 24576){ src=W1b; K=128; M=128; base=8192;  local=id-8192; }
  else if (id < 40960){ src=W2a; K=128; M=128; base=24576; local=id-24576; }
  else if (id < 57344){ src=W2b; K=128; M=128; base=40960; local=id-40960; }
  else if (id < 65536){ src=W3a; K=128; M=64;  base=57344; local=id-57344; }
  else if (id < 69632){ src=W3b; K=64;  M=64;  base=65536; local=id-65536; }
  else if (id < 70656){ src=Wfc; K=64;  M=16;  base=69632; local=id-69632; }
  else return;
  int k = local / M, nn = local - k*M;
  float val;
  if (src == Wfc) val = (nn<8) ? Wfc[k*8+nn] : 0.0f;
  else            val = src[k*M+nn];
  int idx = (((nn>>4)*(K/32) + (k>>5))*4 + ((k>>3)&3))*128 + (nn&15)*8 + (k&7);
  out[base+idx] = f2bf(val);
}

// ------------- x -> bf16 pre-conversion -------------

__global__ __launch_bounds__(256) void k_tobf(const float2* __restrict__ xin, unsigned int* __restrict__ xb, int total2){
  int i = blockIdx.x*256 + threadIdx.x;
  if (i < total2){
    float2 v = xin[i];
    xb[i] = pack2(f2bf(v.x), f2bf(v.y));
  }
}

// ------------- gather L1: bf16 x (N x 32 uints), 2 nodes per wave, unroll x8 -------------

__global__ __launch_bounds__(256) void k_gather64bf(const unsigned int* __restrict__ xb, const int* __restrict__ offs,
                                                    const int* __restrict__ csr, const float* __restrict__ epsp,
                                                    unsigned int* __restrict__ h, int n){
  int gt = blockIdx.x*256 + threadIdx.x;
  int wv = gt >> 6, lane = gt & 63;
  int node = wv*2 + (lane>>5);
  int f = lane & 31;
  if (node >= n) return;
  float e1s = 1.0f + epsp[0];
  unsigned int xv = xb[(size_t)node*32 + f];
  float a0 = e1s*bf2f((unsigned short)(xv & 0xffffu));
  float a1 = e1s*bf2f((unsigned short)(xv >> 16));
  int u0 = offs[node], u1 = offs[node+1];
  int u = u0;
  for (; u+7 < u1; u += 8){
    unsigned int v0 = xb[(size_t)csr[u  ]*32 + f];
    unsigned int v1 = xb[(size_t)csr[u+1]*32 + f];
    unsigned int v2 = xb[(size_t)csr[u+2]*32 + f];
    unsigned int v3 = xb[(size_t)csr[u+3]*32 + f];
    unsigned int v4 = xb[(size_t)csr[u+4]*32 + f];
    unsigned int v5 = xb[(size_t)csr[u+5]*32 + f];
    unsigned int v6 = xb[(size_t)csr[u+6]*32 + f];
    unsigned int v7 = xb[(size_t)csr[u+7]*32 + f];
    a0 += ((bf2f((unsigned short)(v0&0xffffu)) + bf2f((unsigned short)(v1&0xffffu)))
        +  (bf2f((unsigned short)(v2&0xffffu)) + bf2f((unsigned short)(v3&0xffffu))))
        + ((bf2f((unsigned short)(v4&0xffffu)) + bf2f((unsigned short)(v5&0xffffu)))
        +  (bf2f((unsigned short)(v6&0xffffu)) + bf2f((unsigned short)(v7&0xffffu))));
    a1 += ((bf2f((unsigned short)(v0>>16)) + bf2f((unsigned short)(v1>>16)))
        +  (bf2f((unsigned short)(v2>>16)) + bf2f((unsigned short)(v3>>16))))
        + ((bf2f((unsigned short)(v4>>16)) + bf2f((unsigned short)(v5>>16)))
        +  (bf2f((unsigned short)(v6>>16)) + bf2f((unsigned short)(v7>>16))));
  }
  for (; u < u1; ++u){
    unsigned int v = xb[(size_t)csr[u]*32 + f];
    a0 += bf2f((unsigned short)(v & 0xffffu));
    a1 += bf2f((unsigned short)(v >> 16));
  }
  h[(size_t)node*32 + f] = pack2(f2bf(a0), f2bf(a1));
}

// ------------- gather L2/L3: bf16 (uint pairs), F=128, unroll x8 -------------

__global__ __launch_bounds__(256) void k_gather_bf(const unsigned int* __restrict__ x2, const int* __restrict__ offs,
                                                   const int* __restrict__ csr, const float* __restrict__ epsp,
                                                   unsigned int* __restrict__ h2, int n){
  int gt = blockIdx.x*256 + threadIdx.x;
  int node = gt >> 6, lane = gt & 63;
  if (node >= n) return;
  float e1s = 1.0f + epsp[0];
  unsigned int xv = x2[(size_t)node*64 + lane];
  float a0 = e1s*bf2f((unsigned short)(xv & 0xffffu));
  float a1 = e1s*bf2f((unsigned short)(xv >> 16));
  int u0 = offs[node], u1 = offs[node+1];
  int u = u0;
  for (; u+7 < u1; u += 8){
    unsigned int v0 = x2[(size_t)csr[u  ]*64 + lane];
    unsigned int v1 = x2[(size_t)csr[u+1]*64 + lane];
    unsigned int v2 = x2[(size_t)csr[u+2]*64 + lane];
    unsigned int v3 = x2[(size_t)csr[u+3]*64 + lane];
    unsigned int v4 = x2[(size_t)csr[u+4]*64 + lane];
    unsigned int v5 = x2[(size_t)csr[u+5]*64 + lane];
    unsigned int v6 = x2[(size_t)csr[u+6]*64 + lane];
    unsigned int v7 = x2[(size_t)csr[u+7]*64 + lane];
    a0 += ((bf2f((unsigned short)(v0&0xffffu)) + bf2f((unsigned short)(v1&0xffffu)))
        +  (bf2f((unsigned short)(v2&0xffffu)) + bf2f((unsigned short)(v3&0xffffu))))
        + ((bf2f((unsigned short)(v4&0xffffu)) + bf2f((unsigned short)(v5&0xffffu)))
        +  (bf2f((unsigned short)(v6&0xffffu)) + bf2f((unsigned short)(v7&0xffffu))));
    a1 += ((bf2f((unsigned short)(v0>>16)) + bf2f((unsigned short)(v1>>16)))
        +  (bf2f((unsigned short)(v2>>16)) + bf2f((unsigned short)(v3>>16))))
        + ((bf2f((unsigned short)(v4>>16)) + bf2f((unsigned short)(v5>>16)))
        +  (bf2f((unsigned short)(v6>>16)) + bf2f((unsigned short)(v7>>16))));
  }
  for (; u < u1; ++u){
    unsigned int v = x2[(size_t)csr[u]*64 + lane];
    a0 += bf2f((unsigned short)(v & 0xffffu));
    a1 += bf2f((unsigned short)(v >> 16));
  }
  h2[(size_t)node*64 + lane] = pack2(f2bf(a0), f2bf(a1));
}

// ---------------- fused MFMA MLP: x_next = relu(relu(h@Wa+ba)@Wb+bb); LAST adds emb(f32)+FC(f32) ----------------

template<int F, int M1, int M2, bool LAST>
__global__ __launch_bounds__(256)
void k_mlp(const ushort_t* __restrict__ h,
           const ushort_t* __restrict__ wp1, const float* __restrict__ b1,
           const ushort_t* __restrict__ wp2, const float* __restrict__ b2,
           ushort_t* __restrict__ xout,      // !LAST: bf16 next-layer x
           float* __restrict__ embp,         // LAST: f32 emb
           const ushort_t* __restrict__ wpfc, const float* __restrict__ bfc,
           float* __restrict__ outp, int n)
{
  constexpr int NT1 = M1/16, NT2 = M2/16, KC1 = F/32, KC2 = M1/32;
  __shared__ short sC1[4*(M1/8)*136];
  __shared__ short sX3[LAST ? (4*8*136) : 1];
  int tid = threadIdx.x, lane = tid&63, w = tid>>6;
  int m16 = lane&15, quad = lane>>4;
  int row0 = blockIdx.x*64 + w*16;
  size_t arow = (size_t)(row0 + m16);

  floatx4 acc[NT1];
  #pragma unroll
  for (int i=0;i<NT1;++i) acc[i] = (floatx4){0.f,0.f,0.f,0.f};
  #pragma unroll
  for (int kc=0; kc<KC1; ++kc){
    short8 a = *(const short8*)(h + arow*F + kc*32 + quad*8);
    #pragma unroll
    for (int nt=0; nt<NT1; ++nt){
      short8 b = *(const short8*)(wp1 + (size_t)((nt*KC1+kc)*64 + lane)*8);
      acc[nt] = __builtin_amdgcn_mfma_f32_16x16x32_bf16(a, b, acc[nt], 0, 0, 0);
    }
  }
  #pragma unroll
  for (int nt=0; nt<NT1; ++nt){
    int c = nt*16 + m16;
    float bias = b1[c];
    #pragma unroll
    for (int r=0;r<4;++r){
      float v = fmaxf(acc[nt][r] + bias, 0.f);
      int mm = quad*4 + r;
      sC1[(w*(M1/8) + (c>>3))*136 + mm*8 + (c&7)] = (short)f2bf(v);
    }
  }
  __syncthreads();

  floatx4 acc2[NT2];
  #pragma unroll
  for (int i=0;i<NT2;++i) acc2[i] = (floatx4){0.f,0.f,0.f,0.f};
  #pragma unroll
  for (int kc=0; kc<KC2; ++kc){
    short8 a = *(const short8*)&sC1[(w*(M1/8) + kc*4 + quad)*136 + m16*8];
    #pragma unroll
    for (int nt=0; nt<NT2; ++nt){
      short8 b = *(const short8*)(wp2 + (size_t)((nt*KC2+kc)*64 + lane)*8);
      acc2[nt] = __builtin_amdgcn_mfma_f32_16x16x32_bf16(a, b, acc2[nt], 0, 0, 0);
    }
  }
  #pragma unroll
  for (int nt=0; nt<NT2; ++nt){
    int c = nt*16 + m16;
    float bias = b2[c];
    #pragma unroll
    for (int r=0;r<4;++r){
      float v = fmaxf(acc2[nt][r] + bias, 0.f);
      int mm = quad*4 + r;
      int row = row0 + mm;
      if constexpr (!LAST){
        if (row < n) xout[(size_t)row*M2 + c] = f2bf(v);
      } else {
        if (row < n) embp[(size_t)row*64 + c] = v;                // f32 emb
        sX3[(w*8 + (c>>3))*136 + mm*8 + (c&7)] = (short)f2bf(v);
      }
    }
  }

  if constexpr (LAST){
    __syncthreads();
    floatx4 accf = (floatx4){0.f,0.f,0.f,0.f};
    #pragma unroll
    for (int kc=0; kc<2; ++kc){
      short8 a = *(const short8*)&sX3[(w*8 + kc*4 + quad)*136 + m16*8];
      short8 b = *(const short8*)(wpfc + (size_t)(kc*64 + lane)*8);
      accf = __builtin_amdgcn_mfma_f32_16x16x32_bf16(a, b, accf, 0, 0, 0);
    }
    if (m16 < 8){
      float bias = bfc[m16];
      #pragma unroll
      for (int r=0;r<4;++r){
        int row = row0 + quad*4 + r;
        if (row < n) outp[(size_t)row*8 + m16] = accf[r] + bias;  // f32 out
      }
    }
  }
}

// ---------------- launcher ----------------

extern "C" void kernel_launch(void* const* d_in, const int* in_sizes, int n_in,
                              void* d_out, int out_size, void* d_ws, size_t ws_size,
                              hipStream_t stream)
{
  const int N = in_sizes[0] / 64;
  const int E = in_sizes[1] / 2;
  const float*        x    = (const float*)d_in[0];
  const unsigned int* ew   = (const unsigned int*)d_in[1];
  const float* eps1 = (const float*)d_in[2];
  const float* eps2 = (const float*)d_in[3];
  const float* eps3 = (const float*)d_in[4];
  const float* W1a  = (const float*)d_in[5];
  const float* b1a  = (const float*)d_in[6];
  const float* W1b  = (const float*)d_in[7];
  const float* b1b  = (const float*)d_in[8];
  const float* W2a  = (const float*)d_in[9];
  const float* b2a  = (const float*)d_in[10];
  const float* W2b  = (const float*)d_in[11];
  const float* b2b  = (const float*)d_in[12];
  const float* W3a  = (const float*)d_in[13];
  const float* b3a  = (const float*)d_in[14];
  const float* W3b  = (const float*)d_in[15];
  const float* b3b  = (const float*)d_in[16];
  const float* Wfc  = (const float*)d_in[17];
  const float* bfc  = (const float*)d_in[18];

  float* outp = (float*)d_out;                 // f32 output (verified round 6)
  float* emb  = outp + (size_t)N*8;

  const int Npad = ((N + 63)/64)*64;
  const int nb   = (N + 1023)/1024;

  char* ws = (char*)d_ws;
  size_t o = 0;
  auto alloc = [&](size_t bytes)->char* {
    char* p = ws + o;
    o = (o + bytes + 255) & ~(size_t)255;
    return p;
  };
  int*      mode  = (int*)alloc(4);
  int*      deg   = (int*)alloc((size_t)N*4);
  int*      cur   = (int*)alloc((size_t)N*4);
  int*      offs  = (int*)alloc((size_t)(N+1)*4);
  int*      bsum  = (int*)alloc((size_t)nb*4);
  int*      bbase = (int*)alloc((size_t)nb*4);
  int*      csr   = (int*)alloc((size_t)E*4);
  ushort_t* wperm = (ushort_t*)alloc(70656ull*2);
  ushort_t* xb    = (ushort_t*)alloc((size_t)Npad*64*2);    // bf16 copy of x
  ushort_t* hbuf  = (ushort_t*)alloc((size_t)Npad*128*2);   // gather output (bf16)
  ushort_t* x1    = (ushort_t*)alloc((size_t)Npad*128*2);   // layer outputs (bf16)

  hipMemsetAsync(mode, 0, 4, stream);
  hipMemsetAsync(deg, 0, (size_t)N*4, stream);
  k_detect<<<1, 256, 0, stream>>>(ew, mode);
  k_count<<<(E+1023)/1024, 256, 0, stream>>>(ew, mode, deg, E, N);
  k_scan1<<<nb, 256, 0, stream>>>(deg, bsum, N);
  k_scan2<<<1, 128, 0, stream>>>(bsum, bbase, offs + N, nb);
  k_scan3<<<nb, 256, 0, stream>>>(deg, bbase, offs, cur, N);
  k_fill<<<(E+1023)/1024, 256, 0, stream>>>(ew, mode, cur, csr, E, N);
  k_perm<<<(70656+255)/256, 256, 0, stream>>>(W1a, W1b, W2a, W2b, W3a, W3b, Wfc, wperm);
  k_tobf<<<(N*32+255)/256, 256, 0, stream>>>((const float2*)x, (unsigned int*)xb, N*32);

  // layer 1 (64 -> 128)
  k_gather64bf<<<(((N+1)/2)+3)/4, 256, 0, stream>>>((const unsigned int*)xb, offs, csr, eps1,
                                                    (unsigned int*)hbuf, N);
  k_mlp<64,128,128,false><<<Npad/64, 256, 0, stream>>>(hbuf, wperm+0, b1a, wperm+8192, b1b,
                                                       x1, nullptr, nullptr, nullptr, nullptr, N);
  // layer 2 (128 -> 128)
  k_gather_bf<<<(N+3)/4, 256, 0, stream>>>((const unsigned int*)x1, offs, csr, eps2,
                                           (unsigned int*)hbuf, N);
  k_mlp<128,128,128,false><<<Npad/64, 256, 0, stream>>>(hbuf, wperm+24576, b2a, wperm+40960, b2b,
                                                        x1, nullptr, nullptr, nullptr, nullptr, N);
  // layer 3 (128 -> 64) + FC (64 -> 8)
  k_gather_bf<<<(N+3)/4, 256, 0, stream>>>((const unsigned int*)x1, offs, csr, eps3,
                                           (unsigned int*)hbuf, N);
  k_mlp<128,64,64,true><<<Npad/64, 256, 0, stream>>>(hbuf, wperm+57344, b3a, wperm+65536, b3b,
                                                     nullptr, emb, wperm+69632, bfc, outp, N);
}

// Round 10
// 437.088 us; speedup vs baseline: 2.9387x; 1.3335x over previous
//
#include <hip/hip_runtime.h>
#include <hip/hip_bf16.h>
#include <stdint.h>

typedef unsigned short ushort_t;
typedef __attribute__((ext_vector_type(8))) short short8;
typedef __attribute__((ext_vector_type(4))) float floatx4;

__device__ __forceinline__ float bf2f(unsigned short u){
  union { unsigned int i; float f; } v; v.i = ((unsigned int)u) << 16; return v.f;
}
__device__ __forceinline__ unsigned short f2bf(float f){
  union { float f; unsigned int i; } v; v.f = f;
  unsigned int r = v.i + 0x7FFFu + ((v.i >> 16) & 1u);
  return (unsigned short)(r >> 16);
}
__device__ __forceinline__ unsigned int pack2(unsigned short lo, unsigned short hi){
  return ((unsigned int)hi << 16) | (unsigned int)lo;
}

// ------------- edge_index storage detection (int32 words on this harness; probe kept for safety) -------------

__global__ __launch_bounds__(256) void k_detect(const unsigned int* __restrict__ w, int* __restrict__ flag){
  int t = threadIdx.x;
  unsigned int acc = 0;
  #pragma unroll
  for (int i=0;i<16;++i) acc |= w[2*(t*16+i)+1];
  #pragma unroll
  for (int o=32;o>=1;o>>=1) acc |= __shfl_xor(acc, o);
  if ((t&63)==0 && acc) atomicOr(flag, 1);
}

// ---------------- CSR build via 512-node bucket counting sort ----------------
// Buckets: dst>>9, NB = ceil(N/512) <= 256. All same-line csr/offs writes come
// from ONE workgroup (one XCD) so L2 write-combining works — fixes k_fill's
// 105 MB partial-line writeback (134 us -> ~15 us predicted).

// Pass A: global bucket histogram (LDS-staged)
__global__ __launch_bounds__(256) void k_bhist(const unsigned int* __restrict__ w, const int* __restrict__ mode,
                                               int* __restrict__ ghist, int E, int N){
  __shared__ int h[256];
  int t = threadIdx.x;
  h[t] = 0; __syncthreads();
  int m = *mode;
  int base = blockIdx.x*4096 + t;
  #pragma unroll
  for (int i=0;i<16;++i){
    int e = base + i*256;
    if (e < E){
      int d = m ? (int)w[(size_t)E + e] : (int)w[2*((size_t)E + e)];
      if ((unsigned)d < (unsigned)N) atomicAdd(&h[d>>9], 1);
    }
  }
  __syncthreads();
  if (h[t]) atomicAdd(&ghist[t], h[t]);
}

// Pass A2: exclusive scan over NB buckets -> bbase (bucket starts), gcur (cursors)
__global__ __launch_bounds__(256) void k_bscan(const int* __restrict__ ghist, int* __restrict__ bbase,
                                               int* __restrict__ gcur, int NB){
  __shared__ int sv[256];
  int t = threadIdx.x;
  int v = (t < NB) ? ghist[t] : 0;
  sv[t] = v; __syncthreads();
  for (int o=1;o<256;o<<=1){
    int xv = (t>=o)? sv[t-o] : 0;
    __syncthreads();
    sv[t] += xv;
    __syncthreads();
  }
  int excl = sv[t] - v;
  if (t < NB){ bbase[t] = excl; gcur[t] = excl; }
  if (t == NB-1) bbase[NB] = excl + v;   // = E
}

// Pass B: bin (dst,src) pairs into bucket regions; per-(block,bucket) runs are
// contiguous reserved windows -> write-combined.
__global__ __launch_bounds__(256) void k_bin(const unsigned int* __restrict__ w, const int* __restrict__ mode,
                                             int* __restrict__ gcur, int2* __restrict__ pairs,
                                             int E, int N, int NB){
  __shared__ int h[256];
  __shared__ int cur[256];
  int t = threadIdx.x;
  h[t] = 0; __syncthreads();
  int m = *mode;
  int base = blockIdx.x*4096 + t;
  int d[16], s[16];
  #pragma unroll
  for (int i=0;i<16;++i){
    int e = base + i*256;
    d[i] = -1; s[i] = 0;
    if (e < E){
      if (m){ s[i] = (int)w[e];           d[i] = (int)w[(size_t)E + e]; }
      else  { s[i] = (int)w[2*(size_t)e]; d[i] = (int)w[2*((size_t)E + e)]; }
      if ((unsigned)d[i] >= (unsigned)N || (unsigned)s[i] >= (unsigned)N) d[i] = -1;
    }
  }
  #pragma unroll
  for (int i=0;i<16;++i)
    if (d[i] >= 0) atomicAdd(&h[d[i]>>9], 1);
  __syncthreads();
  if (t < NB && h[t]) cur[t] = atomicAdd(&gcur[t], h[t]);
  __syncthreads();
  #pragma unroll
  for (int i=0;i<16;++i){
    if (d[i] >= 0){
      int p = atomicAdd(&cur[d[i]>>9], 1);
      pairs[p] = make_int2(d[i], s[i]);
    }
  }
}

// Pass C: per-bucket degree count + prefix -> offs, then in-bucket scatter -> csr.
__global__ __launch_bounds__(256) void k_bcsr(const int2* __restrict__ pairs, const int* __restrict__ bbase,
                                              int* __restrict__ offs, int* __restrict__ csr, int N, int NB){
  __shared__ int cnt[512];
  __shared__ int wsum[4];
  int b = blockIdx.x, t = threadIdx.x, lane = t&63, wv = t>>6;
  int lo = bbase[b], hi = bbase[b+1];
  int node0 = b << 9;
  cnt[t] = 0; cnt[t+256] = 0;
  __syncthreads();
  for (int i = lo+t; i < hi; i += 256){
    int2 p = pairs[i];
    atomicAdd(&cnt[p.x - node0], 1);
  }
  __syncthreads();
  int v0 = cnt[2*t], v1 = cnt[2*t+1], tot = v0+v1;
  int s = tot;
  #pragma unroll
  for (int o=1;o<64;o<<=1){ int xv = __shfl_up(s,o); if (lane>=o) s += xv; }
  if (lane==63) wsum[wv] = s;
  __syncthreads();                 // also guarantees all cnt reads (v0,v1) are done
  int basev = 0;
  for (int j=0;j<wv;++j) basev += wsum[j];
  int excl = basev + s - tot;
  int e0 = lo + excl, e1 = lo + excl + v0;
  cnt[2*t] = e0; cnt[2*t+1] = e1;  // repurpose as cursors
  int n0 = node0 + 2*t, n1 = node0 + 2*t + 1;
  if (n0 < N) offs[n0] = e0;
  if (n1 < N) offs[n1] = e1;
  if (b == NB-1 && t == 255) offs[N] = hi;   // = E
  __syncthreads();
  for (int i = lo+t; i < hi; i += 256){
    int2 p = pairs[i];
    int pos = atomicAdd(&cnt[p.x - node0], 1);
    csr[pos] = p.y;
  }
}

// ------------- weight permutation: f32 row-major -> bf16 MFMA-B layout -------------

__global__ __launch_bounds__(256) void k_perm(const float* W1a, const float* W1b, const float* W2a,
                                              const float* W2b, const float* W3a, const float* W3b,
                                              const float* Wfc, ushort_t* out){
  int id = blockIdx.x*256 + threadIdx.x;
  const float* src; int K, M, base, local;
  if      (id <  8192){ src=W1a; K=64;  M=128; base=0;     local=id; }
  else if (id < 24576){ src=W1b; K=128; M=128; base=8192;  local=id-8192; }
  else if (id < 40960){ src=W2a; K=128; M=128; base=24576; local=id-24576; }
  else if (id < 57344){ src=W2b; K=128; M=128; base=40960; local=id-40960; }
  else if (id < 65536){ src=W3a; K=128; M=64;  base=57344; local=id-57344; }
  else if (id < 69632){ src=W3b; K=64;  M=64;  base=65536; local=id-65536; }
  else if (id < 70656){ src=Wfc; K=64;  M=16;  base=69632; local=id-69632; }
  else return;
  int k = local / M, nn = local - k*M;
  float val;
  if (src == Wfc) val = (nn<8) ? Wfc[k*8+nn] : 0.0f;
  else            val = src[k*M+nn];
  int idx = (((nn>>4)*(K/32) + (k>>5))*4 + ((k>>3)&3))*128 + (nn&15)*8 + (k&7);
  out[base+idx] = f2bf(val);
}

// ------------- x -> bf16 pre-conversion -------------

__global__ __launch_bounds__(256) void k_tobf(const float2* __restrict__ xin, unsigned int* __restrict__ xb, int total2){
  int i = blockIdx.x*256 + threadIdx.x;
  if (i < total2){
    float2 v = xin[i];
    xb[i] = pack2(f2bf(v.x), f2bf(v.y));
  }
}

// ------------- gather L1: bf16 x (N x 32 uints), 2 nodes per wave, unroll x8 -------------

__global__ __launch_bounds__(256) void k_gather64bf(const unsigned int* __restrict__ xb, const int* __restrict__ offs,
                                                    const int* __restrict__ csr, const float* __restrict__ epsp,
                                                    unsigned int* __restrict__ h, int n){
  int gt = blockIdx.x*256 + threadIdx.x;
  int wv = gt >> 6, lane = gt & 63;
  int node = wv*2 + (lane>>5);
  int f = lane & 31;
  if (node >= n) return;
  float e1s = 1.0f + epsp[0];
  unsigned int xv = xb[(size_t)node*32 + f];
  float a0 = e1s*bf2f((unsigned short)(xv & 0xffffu));
  float a1 = e1s*bf2f((unsigned short)(xv >> 16));
  int u0 = offs[node], u1 = offs[node+1];
  int u = u0;
  for (; u+7 < u1; u += 8){
    unsigned int v0 = xb[(size_t)csr[u  ]*32 + f];
    unsigned int v1 = xb[(size_t)csr[u+1]*32 + f];
    unsigned int v2 = xb[(size_t)csr[u+2]*32 + f];
    unsigned int v3 = xb[(size_t)csr[u+3]*32 + f];
    unsigned int v4 = xb[(size_t)csr[u+4]*32 + f];
    unsigned int v5 = xb[(size_t)csr[u+5]*32 + f];
    unsigned int v6 = xb[(size_t)csr[u+6]*32 + f];
    unsigned int v7 = xb[(size_t)csr[u+7]*32 + f];
    a0 += ((bf2f((unsigned short)(v0&0xffffu)) + bf2f((unsigned short)(v1&0xffffu)))
        +  (bf2f((unsigned short)(v2&0xffffu)) + bf2f((unsigned short)(v3&0xffffu))))
        + ((bf2f((unsigned short)(v4&0xffffu)) + bf2f((unsigned short)(v5&0xffffu)))
        +  (bf2f((unsigned short)(v6&0xffffu)) + bf2f((unsigned short)(v7&0xffffu))));
    a1 += ((bf2f((unsigned short)(v0>>16)) + bf2f((unsigned short)(v1>>16)))
        +  (bf2f((unsigned short)(v2>>16)) + bf2f((unsigned short)(v3>>16))))
        + ((bf2f((unsigned short)(v4>>16)) + bf2f((unsigned short)(v5>>16)))
        +  (bf2f((unsigned short)(v6>>16)) + bf2f((unsigned short)(v7>>16))));
  }
  for (; u < u1; ++u){
    unsigned int v = xb[(size_t)csr[u]*32 + f];
    a0 += bf2f((unsigned short)(v & 0xffffu));
    a1 += bf2f((unsigned short)(v >> 16));
  }
  h[(size_t)node*32 + f] = pack2(f2bf(a0), f2bf(a1));
}

// ------------- gather L2/L3: bf16 (uint pairs), F=128, unroll x8 -------------

__global__ __launch_bounds__(256) void k_gather_bf(const unsigned int* __restrict__ x2, const int* __restrict__ offs,
                                                   const int* __restrict__ csr, const float* __restrict__ epsp,
                                                   unsigned int* __restrict__ h2, int n){
  int gt = blockIdx.x*256 + threadIdx.x;
  int node = gt >> 6, lane = gt & 63;
  if (node >= n) return;
  float e1s = 1.0f + epsp[0];
  unsigned int xv = x2[(size_t)node*64 + lane];
  float a0 = e1s*bf2f((unsigned short)(xv & 0xffffu));
  float a1 = e1s*bf2f((unsigned short)(xv >> 16));
  int u0 = offs[node], u1 = offs[node+1];
  int u = u0;
  for (; u+7 < u1; u += 8){
    unsigned int v0 = x2[(size_t)csr[u  ]*64 + lane];
    unsigned int v1 = x2[(size_t)csr[u+1]*64 + lane];
    unsigned int v2 = x2[(size_t)csr[u+2]*64 + lane];
    unsigned int v3 = x2[(size_t)csr[u+3]*64 + lane];
    unsigned int v4 = x2[(size_t)csr[u+4]*64 + lane];
    unsigned int v5 = x2[(size_t)csr[u+5]*64 + lane];
    unsigned int v6 = x2[(size_t)csr[u+6]*64 + lane];
    unsigned int v7 = x2[(size_t)csr[u+7]*64 + lane];
    a0 += ((bf2f((unsigned short)(v0&0xffffu)) + bf2f((unsigned short)(v1&0xffffu)))
        +  (bf2f((unsigned short)(v2&0xffffu)) + bf2f((unsigned short)(v3&0xffffu))))
        + ((bf2f((unsigned short)(v4&0xffffu)) + bf2f((unsigned short)(v5&0xffffu)))
        +  (bf2f((unsigned short)(v6&0xffffu)) + bf2f((unsigned short)(v7&0xffffu))));
    a1 += ((bf2f((unsigned short)(v0>>16)) + bf2f((unsigned short)(v1>>16)))
        +  (bf2f((unsigned short)(v2>>16)) + bf2f((unsigned short)(v3>>16))))
        + ((bf2f((unsigned short)(v4>>16)) + bf2f((unsigned short)(v5>>16)))
        +  (bf2f((unsigned short)(v6>>16)) + bf2f((unsigned short)(v7>>16))));
  }
  for (; u < u1; ++u){
    unsigned int v = x2[(size_t)csr[u]*64 + lane];
    a0 += bf2f((unsigned short)(v & 0xffffu));
    a1 += bf2f((unsigned short)(v >> 16));
  }
  h2[(size_t)node*64 + lane] = pack2(f2bf(a0), f2bf(a1));
}

// ---------------- fused MFMA MLP: x_next = relu(relu(h@Wa+ba)@Wb+bb); LAST adds emb(f32)+FC(f32) ----------------

template<int F, int M1, int M2, bool LAST>
__global__ __launch_bounds__(256)
void k_mlp(const ushort_t* __restrict__ h,
           const ushort_t* __restrict__ wp1, const float* __restrict__ b1,
           const ushort_t* __restrict__ wp2, const float* __restrict__ b2,
           ushort_t* __restrict__ xout,      // !LAST: bf16 next-layer x
           float* __restrict__ embp,         // LAST: f32 emb
           const ushort_t* __restrict__ wpfc, const float* __restrict__ bfc,
           float* __restrict__ outp, int n)
{
  constexpr int NT1 = M1/16, NT2 = M2/16, KC1 = F/32, KC2 = M1/32;
  __shared__ short sC1[4*(M1/8)*136];
  __shared__ short sX3[LAST ? (4*8*136) : 1];
  int tid = threadIdx.x, lane = tid&63, w = tid>>6;
  int m16 = lane&15, quad = lane>>4;
  int row0 = blockIdx.x*64 + w*16;
  size_t arow = (size_t)(row0 + m16);

  floatx4 acc[NT1];
  #pragma unroll
  for (int i=0;i<NT1;++i) acc[i] = (floatx4){0.f,0.f,0.f,0.f};
  #pragma unroll
  for (int kc=0; kc<KC1; ++kc){
    short8 a = *(const short8*)(h + arow*F + kc*32 + quad*8);
    #pragma unroll
    for (int nt=0; nt<NT1; ++nt){
      short8 b = *(const short8*)(wp1 + (size_t)((nt*KC1+kc)*64 + lane)*8);
      acc[nt] = __builtin_amdgcn_mfma_f32_16x16x32_bf16(a, b, acc[nt], 0, 0, 0);
    }
  }
  #pragma unroll
  for (int nt=0; nt<NT1; ++nt){
    int c = nt*16 + m16;
    float bias = b1[c];
    #pragma unroll
    for (int r=0;r<4;++r){
      float v = fmaxf(acc[nt][r] + bias, 0.f);
      int mm = quad*4 + r;
      sC1[(w*(M1/8) + (c>>3))*136 + mm*8 + (c&7)] = (short)f2bf(v);
    }
  }
  __syncthreads();

  floatx4 acc2[NT2];
  #pragma unroll
  for (int i=0;i<NT2;++i) acc2[i] = (floatx4){0.f,0.f,0.f,0.f};
  #pragma unroll
  for (int kc=0; kc<KC2; ++kc){
    short8 a = *(const short8*)&sC1[(w*(M1/8) + kc*4 + quad)*136 + m16*8];
    #pragma unroll
    for (int nt=0; nt<NT2; ++nt){
      short8 b = *(const short8*)(wp2 + (size_t)((nt*KC2+kc)*64 + lane)*8);
      acc2[nt] = __builtin_amdgcn_mfma_f32_16x16x32_bf16(a, b, acc2[nt], 0, 0, 0);
    }
  }
  #pragma unroll
  for (int nt=0; nt<NT2; ++nt){
    int c = nt*16 + m16;
    float bias = b2[c];
    #pragma unroll
    for (int r=0;r<4;++r){
      float v = fmaxf(acc2[nt][r] + bias, 0.f);
      int mm = quad*4 + r;
      int row = row0 + mm;
      if constexpr (!LAST){
        if (row < n) xout[(size_t)row*M2 + c] = f2bf(v);
      } else {
        if (row < n) embp[(size_t)row*64 + c] = v;                // f32 emb
        sX3[(w*8 + (c>>3))*136 + mm*8 + (c&7)] = (short)f2bf(v);
      }
    }
  }

  if constexpr (LAST){
    __syncthreads();
    floatx4 accf = (floatx4){0.f,0.f,0.f,0.f};
    #pragma unroll
    for (int kc=0; kc<2; ++kc){
      short8 a = *(const short8*)&sX3[(w*8 + kc*4 + quad)*136 + m16*8];
      short8 b = *(const short8*)(wpfc + (size_t)(kc*64 + lane)*8);
      accf = __builtin_amdgcn_mfma_f32_16x16x32_bf16(a, b, accf, 0, 0, 0);
    }
    if (m16 < 8){
      float bias = bfc[m16];
      #pragma unroll
      for (int r=0;r<4;++r){
        int row = row0 + quad*4 + r;
        if (row < n) outp[(size_t)row*8 + m16] = accf[r] + bias;  // f32 out
      }
    }
  }
}

// ---------------- launcher ----------------

extern "C" void kernel_launch(void* const* d_in, const int* in_sizes, int n_in,
                              void* d_out, int out_size, void* d_ws, size_t ws_size,
                              hipStream_t stream)
{
  const int N = in_sizes[0] / 64;
  const int E = in_sizes[1] / 2;
  const int NB = (N + 511) / 512;            // <= 256 for N <= 131072
  const float*        x    = (const float*)d_in[0];
  const unsigned int* ew   = (const unsigned int*)d_in[1];
  const float* eps1 = (const float*)d_in[2];
  const float* eps2 = (const float*)d_in[3];
  const float* eps3 = (const float*)d_in[4];
  const float* W1a  = (const float*)d_in[5];
  const float* b1a  = (const float*)d_in[6];
  const float* W1b  = (const float*)d_in[7];
  const float* b1b  = (const float*)d_in[8];
  const float* W2a  = (const float*)d_in[9];
  const float* b2a  = (const float*)d_in[10];
  const float* W2b  = (const float*)d_in[11];
  const float* b2b  = (const float*)d_in[12];
  const float* W3a  = (const float*)d_in[13];
  const float* b3a  = (const float*)d_in[14];
  const float* W3b  = (const float*)d_in[15];
  const float* b3b  = (const float*)d_in[16];
  const float* Wfc  = (const float*)d_in[17];
  const float* bfc  = (const float*)d_in[18];

  float* outp = (float*)d_out;                 // f32 output (verified round 6)
  float* emb  = outp + (size_t)N*8;

  const int Npad = ((N + 63)/64)*64;

  char* ws = (char*)d_ws;
  size_t o = 0;
  auto alloc = [&](size_t bytes)->char* {
    char* p = ws + o;
    o = (o + bytes + 255) & ~(size_t)255;
    return p;
  };
  int*      mode  = (int*)alloc(4);
  int*      ghist = (int*)alloc(256*4);
  int*      bbase = (int*)alloc(257*4);
  int*      gcur  = (int*)alloc(256*4);
  int*      offs  = (int*)alloc((size_t)(N+1)*4);
  int2*     pairs = (int2*)alloc((size_t)E*8);
  int*      csr   = (int*)alloc((size_t)E*4);
  ushort_t* wperm = (ushort_t*)alloc(70656ull*2);
  ushort_t* xb    = (ushort_t*)alloc((size_t)Npad*64*2);    // bf16 copy of x
  ushort_t* hbuf  = (ushort_t*)alloc((size_t)Npad*128*2);   // gather output (bf16)
  ushort_t* x1    = (ushort_t*)alloc((size_t)Npad*128*2);   // layer outputs (bf16)

  hipMemsetAsync(mode, 0, 4, stream);
  hipMemsetAsync(ghist, 0, 256*4, stream);
  k_detect<<<1, 256, 0, stream>>>(ew, mode);
  const int nbB = (E + 4095)/4096;
  k_bhist<<<nbB, 256, 0, stream>>>(ew, mode, ghist, E, N);
  k_bscan<<<1, 256, 0, stream>>>(ghist, bbase, gcur, NB);
  k_bin<<<nbB, 256, 0, stream>>>(ew, mode, gcur, pairs, E, N, NB);
  k_bcsr<<<NB, 256, 0, stream>>>(pairs, bbase, offs, csr, N, NB);
  k_perm<<<(70656+255)/256, 256, 0, stream>>>(W1a, W1b, W2a, W2b, W3a, W3b, Wfc, wperm);
  k_tobf<<<(N*32+255)/256, 256, 0, stream>>>((const float2*)x, (unsigned int*)xb, N*32);

  // layer 1 (64 -> 128)
  k_gather64bf<<<(((N+1)/2)+3)/4, 256, 0, stream>>>((const unsigned int*)xb, offs, csr, eps1,
                                                    (unsigned int*)hbuf, N);
  k_mlp<64,128,128,false><<<Npad/64, 256, 0, stream>>>(hbuf, wperm+0, b1a, wperm+8192, b1b,
                                                       x1, nullptr, nullptr, nullptr, nullptr, N);
  // layer 2 (128 -> 128)
  k_gather_bf<<<(N+3)/4, 256, 0, stream>>>((const unsigned int*)x1, offs, csr, eps2,
                                           (unsigned int*)hbuf, N);
  k_mlp<128,128,128,false><<<Npad/64, 256, 0, stream>>>(hbuf, wperm+24576, b2a, wperm+40960, b2b,
                                                        x1, nullptr, nullptr, nullptr, nullptr, N);
  // layer 3 (128 -> 64) + FC (64 -> 8)
  k_gather_bf<<<(N+3)/4, 256, 0, stream>>>((const unsigned int*)x1, offs, csr, eps3,
                                           (unsigned int*)hbuf, N);
  k_mlp<128,64,64,true><<<Npad/64, 256, 0, stream>>>(hbuf, wperm+57344, b3a, wperm+65536, b3b,
                                                     nullptr, emb, wperm+69632, bfc, outp, N);
}

// Round 11
// 424.662 us; speedup vs baseline: 3.0247x; 1.0293x over previous
//
#include <hip/hip_runtime.h>
#include <hip/hip_bf16.h>
#include <stdint.h>

typedef unsigned short ushort_t;
typedef __attribute__((ext_vector_type(8))) short short8;
typedef __attribute__((ext_vector_type(4))) float floatx4;

__device__ __forceinline__ float bf2f(unsigned short u){
  union { unsigned int i; float f; } v; v.i = ((unsigned int)u) << 16; return v.f;
}
__device__ __forceinline__ unsigned short f2bf(float f){
  union { float f; unsigned int i; } v; v.f = f;
  unsigned int r = v.i + 0x7FFFu + ((v.i >> 16) & 1u);
  return (unsigned short)(r >> 16);
}
__device__ __forceinline__ unsigned int pack2(unsigned short lo, unsigned short hi){
  return ((unsigned int)hi << 16) | (unsigned int)lo;
}

// ------------- edge_index storage detection (int32 words on this harness; probe kept for safety) -------------

__global__ __launch_bounds__(256) void k_detect(const unsigned int* __restrict__ w, int* __restrict__ flag){
  int t = threadIdx.x;
  unsigned int acc = 0;
  #pragma unroll
  for (int i=0;i<16;++i) acc |= w[2*(t*16+i)+1];
  #pragma unroll
  for (int o=32;o>=1;o>>=1) acc |= __shfl_xor(acc, o);
  if ((t&63)==0 && acc) atomicOr(flag, 1);
}

// ---------------- CSR build via 512-node bucket counting sort ----------------
// (round 10: replaced atomic k_fill — its 105 MB partial-line writeback was the #1 dispatch)

__global__ __launch_bounds__(256) void k_bhist(const unsigned int* __restrict__ w, const int* __restrict__ mode,
                                               int* __restrict__ ghist, int E, int N){
  __shared__ int h[256];
  int t = threadIdx.x;
  h[t] = 0; __syncthreads();
  int m = *mode;
  int base = blockIdx.x*4096 + t;
  #pragma unroll
  for (int i=0;i<16;++i){
    int e = base + i*256;
    if (e < E){
      int d = m ? (int)w[(size_t)E + e] : (int)w[2*((size_t)E + e)];
      if ((unsigned)d < (unsigned)N) atomicAdd(&h[d>>9], 1);
    }
  }
  __syncthreads();
  if (h[t]) atomicAdd(&ghist[t], h[t]);
}

__global__ __launch_bounds__(256) void k_bscan(const int* __restrict__ ghist, int* __restrict__ bbase,
                                               int* __restrict__ gcur, int NB){
  __shared__ int sv[256];
  int t = threadIdx.x;
  int v = (t < NB) ? ghist[t] : 0;
  sv[t] = v; __syncthreads();
  for (int o=1;o<256;o<<=1){
    int xv = (t>=o)? sv[t-o] : 0;
    __syncthreads();
    sv[t] += xv;
    __syncthreads();
  }
  int excl = sv[t] - v;
  if (t < NB){ bbase[t] = excl; gcur[t] = excl; }
  if (t == NB-1) bbase[NB] = excl + v;
}

__global__ __launch_bounds__(256) void k_bin(const unsigned int* __restrict__ w, const int* __restrict__ mode,
                                             int* __restrict__ gcur, int2* __restrict__ pairs,
                                             int E, int N, int NB){
  __shared__ int h[256];
  __shared__ int cur[256];
  int t = threadIdx.x;
  h[t] = 0; __syncthreads();
  int m = *mode;
  int base = blockIdx.x*4096 + t;
  int d[16], s[16];
  #pragma unroll
  for (int i=0;i<16;++i){
    int e = base + i*256;
    d[i] = -1; s[i] = 0;
    if (e < E){
      if (m){ s[i] = (int)w[e];           d[i] = (int)w[(size_t)E + e]; }
      else  { s[i] = (int)w[2*(size_t)e]; d[i] = (int)w[2*((size_t)E + e)]; }
      if ((unsigned)d[i] >= (unsigned)N || (unsigned)s[i] >= (unsigned)N) d[i] = -1;
    }
  }
  #pragma unroll
  for (int i=0;i<16;++i)
    if (d[i] >= 0) atomicAdd(&h[d[i]>>9], 1);
  __syncthreads();
  if (t < NB && h[t]) cur[t] = atomicAdd(&gcur[t], h[t]);
  __syncthreads();
  #pragma unroll
  for (int i=0;i<16;++i){
    if (d[i] >= 0){
      int p = atomicAdd(&cur[d[i]>>9], 1);
      pairs[p] = make_int2(d[i], s[i]);
    }
  }
}

__global__ __launch_bounds__(256) void k_bcsr(const int2* __restrict__ pairs, const int* __restrict__ bbase,
                                              int* __restrict__ offs, int* __restrict__ csr, int N, int NB){
  __shared__ int cnt[512];
  __shared__ int wsum[4];
  int b = blockIdx.x, t = threadIdx.x, lane = t&63, wv = t>>6;
  int lo = bbase[b], hi = bbase[b+1];
  int node0 = b << 9;
  cnt[t] = 0; cnt[t+256] = 0;
  __syncthreads();
  for (int i = lo+t; i < hi; i += 256){
    int2 p = pairs[i];
    atomicAdd(&cnt[p.x - node0], 1);
  }
  __syncthreads();
  int v0 = cnt[2*t], v1 = cnt[2*t+1], tot = v0+v1;
  int s = tot;
  #pragma unroll
  for (int o=1;o<64;o<<=1){ int xv = __shfl_up(s,o); if (lane>=o) s += xv; }
  if (lane==63) wsum[wv] = s;
  __syncthreads();
  int basev = 0;
  for (int j=0;j<wv;++j) basev += wsum[j];
  int excl = basev + s - tot;
  int e0 = lo + excl, e1 = lo + excl + v0;
  cnt[2*t] = e0; cnt[2*t+1] = e1;
  int n0 = node0 + 2*t, n1 = node0 + 2*t + 1;
  if (n0 < N) offs[n0] = e0;
  if (n1 < N) offs[n1] = e1;
  if (b == NB-1 && t == 255) offs[N] = hi;
  __syncthreads();
  for (int i = lo+t; i < hi; i += 256){
    int2 p = pairs[i];
    int pos = atomicAdd(&cnt[p.x - node0], 1);
    csr[pos] = p.y;
  }
}

// ------------- weight permutation: f32 row-major -> bf16 MFMA-B layout -------------

__global__ __launch_bounds__(256) void k_perm(const float* W1a, const float* W1b, const float* W2a,
                                              const float* W2b, const float* W3a, const float* W3b,
                                              const float* Wfc, ushort_t* out){
  int id = blockIdx.x*256 + threadIdx.x;
  const float* src; int K, M, base, local;
  if      (id <  8192){ src=W1a; K=64;  M=128; base=0;     local=id; }
  else if (id < 24576){ src=W1b; K=128; M=128; base=8192;  local=id-8192; }
  else if (id < 40960){ src=W2a; K=128; M=128; base=24576; local=id-24576; }
  else if (id < 57344){ src=W2b; K=128; M=128; base=40960; local=id-40960; }
  else if (id < 65536){ src=W3a; K=128; M=64;  base=57344; local=id-57344; }
  else if (id < 69632){ src=W3b; K=64;  M=64;  base=65536; local=id-65536; }
  else if (id < 70656){ src=Wfc; K=64;  M=16;  base=69632; local=id-69632; }
  else return;
  int k = local / M, nn = local - k*M;
  float val;
  if (src == Wfc) val = (nn<8) ? Wfc[k*8+nn] : 0.0f;
  else            val = src[k*M+nn];
  int idx = (((nn>>4)*(K/32) + (k>>5))*4 + ((k>>3)&3))*128 + (nn&15)*8 + (k&7);
  out[base+idx] = f2bf(val);
}

// ------------- x -> bf16 pre-conversion -------------

__global__ __launch_bounds__(256) void k_tobf(const float2* __restrict__ xin, unsigned int* __restrict__ xb, int total2){
  int i = blockIdx.x*256 + threadIdx.x;
  if (i < total2){
    float2 v = xin[i];
    xb[i] = pack2(f2bf(v.x), f2bf(v.y));
  }
}

// ------------- gather (both F): half-row-pair scheme -------------
// G = F/4 lanes cover one 256B/128B row via uint2 (8B) loads. The two halves of a
// node's lane-group process interleaved edges (identical trip counts -> no divergence),
// folded at the end via shfl_xor(G). Unroll x8 edges = 4 uint2 loads in flight per half.

template<int F>
__global__ __launch_bounds__(256) void k_gatherx(const uint2* __restrict__ xr, const int* __restrict__ offs,
                                                 const int* __restrict__ csr, const float* __restrict__ epsp,
                                                 uint2* __restrict__ hr, int n){
  constexpr int G = F/4;           // lanes per row (uint2 each): 32 (F=128), 16 (F=64)
  constexpr int NPW = 64/(2*G);    // nodes per wave: 1 (F=128), 2 (F=64)
  int gt = blockIdx.x*256 + threadIdx.x;
  int wv = gt >> 6, lane = gt & 63;
  int grp  = lane / (2*G);
  int half = (lane / G) & 1;
  int f    = lane % G;
  int node = wv*NPW + grp;
  if (node >= n) return;
  const size_t row = (size_t)node*G;
  uint2 sv = xr[row + f];
  float e1s = 1.0f + epsp[0];
  float a0, a1, a2, a3;
  if (half == 0){
    a0 = e1s*bf2f((ushort_t)(sv.x & 0xffffu)); a1 = e1s*bf2f((ushort_t)(sv.x >> 16));
    a2 = e1s*bf2f((ushort_t)(sv.y & 0xffffu)); a3 = e1s*bf2f((ushort_t)(sv.y >> 16));
  } else { a0 = a1 = a2 = a3 = 0.f; }
  int u0 = offs[node], u1 = offs[node+1];
  int u = u0;
#define ACC4(v) { a0 += bf2f((ushort_t)((v).x & 0xffffu)); a1 += bf2f((ushort_t)((v).x >> 16)); \
                  a2 += bf2f((ushort_t)((v).y & 0xffffu)); a3 += bf2f((ushort_t)((v).y >> 16)); }
  for (; u+7 < u1; u += 8){
    int s0 = csr[u   + half];
    int s1 = csr[u+2 + half];
    int s2 = csr[u+4 + half];
    int s3 = csr[u+6 + half];
    uint2 v0 = xr[(size_t)s0*G + f];
    uint2 v1 = xr[(size_t)s1*G + f];
    uint2 v2 = xr[(size_t)s2*G + f];
    uint2 v3 = xr[(size_t)s3*G + f];
    ACC4(v0) ACC4(v1) ACC4(v2) ACC4(v3)
  }
  for (; u+1 < u1; u += 2){
    int s = csr[u + half];
    uint2 v = xr[(size_t)s*G + f];
    ACC4(v)
  }
  if (u < u1 && half == 0){
    int s = csr[u];
    uint2 v = xr[(size_t)s*G + f];
    ACC4(v)
  }
#undef ACC4
  a0 += __shfl_xor(a0, G);
  a1 += __shfl_xor(a1, G);
  a2 += __shfl_xor(a2, G);
  a3 += __shfl_xor(a3, G);
  if (half == 0){
    uint2 o2;
    o2.x = pack2(f2bf(a0), f2bf(a1));
    o2.y = pack2(f2bf(a2), f2bf(a3));
    hr[row + f] = o2;
  }
}

// ---------------- fused MFMA MLP: x_next = relu(relu(h@Wa+ba)@Wb+bb); LAST adds emb(f32)+FC(f32) ----------------

template<int F, int M1, int M2, bool LAST>
__global__ __launch_bounds__(256)
void k_mlp(const ushort_t* __restrict__ h,
           const ushort_t* __restrict__ wp1, const float* __restrict__ b1,
           const ushort_t* __restrict__ wp2, const float* __restrict__ b2,
           ushort_t* __restrict__ xout,      // !LAST: bf16 next-layer x
           float* __restrict__ embp,         // LAST: f32 emb
           const ushort_t* __restrict__ wpfc, const float* __restrict__ bfc,
           float* __restrict__ outp, int n)
{
  constexpr int NT1 = M1/16, NT2 = M2/16, KC1 = F/32, KC2 = M1/32;
  __shared__ short sC1[4*(M1/8)*136];
  __shared__ short sX3[LAST ? (4*8*136) : 1];
  int tid = threadIdx.x, lane = tid&63, w = tid>>6;
  int m16 = lane&15, quad = lane>>4;
  int row0 = blockIdx.x*64 + w*16;
  size_t arow = (size_t)(row0 + m16);

  floatx4 acc[NT1];
  #pragma unroll
  for (int i=0;i<NT1;++i) acc[i] = (floatx4){0.f,0.f,0.f,0.f};
  #pragma unroll
  for (int kc=0; kc<KC1; ++kc){
    short8 a = *(const short8*)(h + arow*F + kc*32 + quad*8);
    #pragma unroll
    for (int nt=0; nt<NT1; ++nt){
      short8 b = *(const short8*)(wp1 + (size_t)((nt*KC1+kc)*64 + lane)*8);
      acc[nt] = __builtin_amdgcn_mfma_f32_16x16x32_bf16(a, b, acc[nt], 0, 0, 0);
    }
  }
  #pragma unroll
  for (int nt=0; nt<NT1; ++nt){
    int c = nt*16 + m16;
    float bias = b1[c];
    #pragma unroll
    for (int r=0;r<4;++r){
      float v = fmaxf(acc[nt][r] + bias, 0.f);
      int mm = quad*4 + r;
      sC1[(w*(M1/8) + (c>>3))*136 + mm*8 + (c&7)] = (short)f2bf(v);
    }
  }
  __syncthreads();

  floatx4 acc2[NT2];
  #pragma unroll
  for (int i=0;i<NT2;++i) acc2[i] = (floatx4){0.f,0.f,0.f,0.f};
  #pragma unroll
  for (int kc=0; kc<KC2; ++kc){
    short8 a = *(const short8*)&sC1[(w*(M1/8) + kc*4 + quad)*136 + m16*8];
    #pragma unroll
    for (int nt=0; nt<NT2; ++nt){
      short8 b = *(const short8*)(wp2 + (size_t)((nt*KC2+kc)*64 + lane)*8);
      acc2[nt] = __builtin_amdgcn_mfma_f32_16x16x32_bf16(a, b, acc2[nt], 0, 0, 0);
    }
  }
  #pragma unroll
  for (int nt=0; nt<NT2; ++nt){
    int c = nt*16 + m16;
    float bias = b2[c];
    #pragma unroll
    for (int r=0;r<4;++r){
      float v = fmaxf(acc2[nt][r] + bias, 0.f);
      int mm = quad*4 + r;
      int row = row0 + mm;
      if constexpr (!LAST){
        if (row < n) xout[(size_t)row*M2 + c] = f2bf(v);
      } else {
        if (row < n) embp[(size_t)row*64 + c] = v;                // f32 emb
        sX3[(w*8 + (c>>3))*136 + mm*8 + (c&7)] = (short)f2bf(v);
      }
    }
  }

  if constexpr (LAST){
    __syncthreads();
    floatx4 accf = (floatx4){0.f,0.f,0.f,0.f};
    #pragma unroll
    for (int kc=0; kc<2; ++kc){
      short8 a = *(const short8*)&sX3[(w*8 + kc*4 + quad)*136 + m16*8];
      short8 b = *(const short8*)(wpfc + (size_t)(kc*64 + lane)*8);
      accf = __builtin_amdgcn_mfma_f32_16x16x32_bf16(a, b, accf, 0, 0, 0);
    }
    if (m16 < 8){
      float bias = bfc[m16];
      #pragma unroll
      for (int r=0;r<4;++r){
        int row = row0 + quad*4 + r;
        if (row < n) outp[(size_t)row*8 + m16] = accf[r] + bias;  // f32 out
      }
    }
  }
}

// ---------------- launcher ----------------

extern "C" void kernel_launch(void* const* d_in, const int* in_sizes, int n_in,
                              void* d_out, int out_size, void* d_ws, size_t ws_size,
                              hipStream_t stream)
{
  const int N = in_sizes[0] / 64;
  const int E = in_sizes[1] / 2;
  const int NB = (N + 511) / 512;
  const float*        x    = (const float*)d_in[0];
  const unsigned int* ew   = (const unsigned int*)d_in[1];
  const float* eps1 = (const float*)d_in[2];
  const float* eps2 = (const float*)d_in[3];
  const float* eps3 = (const float*)d_in[4];
  const float* W1a  = (const float*)d_in[5];
  const float* b1a  = (const float*)d_in[6];
  const float* W1b  = (const float*)d_in[7];
  const float* b1b  = (const float*)d_in[8];
  const float* W2a  = (const float*)d_in[9];
  const float* b2a  = (const float*)d_in[10];
  const float* W2b  = (const float*)d_in[11];
  const float* b2b  = (const float*)d_in[12];
  const float* W3a  = (const float*)d_in[13];
  const float* b3a  = (const float*)d_in[14];
  const float* W3b  = (const float*)d_in[15];
  const float* b3b  = (const float*)d_in[16];
  const float* Wfc  = (const float*)d_in[17];
  const float* bfc  = (const float*)d_in[18];

  float* outp = (float*)d_out;                 // f32 output (verified round 6)
  float* emb  = outp + (size_t)N*8;

  const int Npad = ((N + 63)/64)*64;

  char* ws = (char*)d_ws;
  size_t o = 0;
  auto alloc = [&](size_t bytes)->char* {
    char* p = ws + o;
    o = (o + bytes + 255) & ~(size_t)255;
    return p;
  };
  int*      mode  = (int*)alloc(4);
  int*      ghist = (int*)alloc(256*4);
  int*      bbase = (int*)alloc(257*4);
  int*      gcur  = (int*)alloc(256*4);
  int*      offs  = (int*)alloc((size_t)(N+1)*4);
  int2*     pairs = (int2*)alloc((size_t)E*8);
  int*      csr   = (int*)alloc((size_t)E*4);
  ushort_t* wperm = (ushort_t*)alloc(70656ull*2);
  ushort_t* xb    = (ushort_t*)alloc((size_t)Npad*64*2);    // bf16 copy of x
  ushort_t* hbuf  = (ushort_t*)alloc((size_t)Npad*128*2);   // gather output (bf16)
  ushort_t* x1    = (ushort_t*)alloc((size_t)Npad*128*2);   // layer outputs (bf16)

  hipMemsetAsync(mode, 0, 4, stream);
  hipMemsetAsync(ghist, 0, 256*4, stream);
  k_detect<<<1, 256, 0, stream>>>(ew, mode);
  const int nbB = (E + 4095)/4096;
  k_bhist<<<nbB, 256, 0, stream>>>(ew, mode, ghist, E, N);
  k_bscan<<<1, 256, 0, stream>>>(ghist, bbase, gcur, NB);
  k_bin<<<nbB, 256, 0, stream>>>(ew, mode, gcur, pairs, E, N, NB);
  k_bcsr<<<NB, 256, 0, stream>>>(pairs, bbase, offs, csr, N, NB);
  k_perm<<<(70656+255)/256, 256, 0, stream>>>(W1a, W1b, W2a, W2b, W3a, W3b, Wfc, wperm);
  k_tobf<<<(N*32+255)/256, 256, 0, stream>>>((const float2*)x, (unsigned int*)xb, N*32);

  // layer 1 (64 -> 128): gather F=64 (2 nodes/wave)
  k_gatherx<64><<<(((N+1)/2)+3)/4, 256, 0, stream>>>((const uint2*)xb, offs, csr, eps1,
                                                     (uint2*)hbuf, N);
  k_mlp<64,128,128,false><<<Npad/64, 256, 0, stream>>>(hbuf, wperm+0, b1a, wperm+8192, b1b,
                                                       x1, nullptr, nullptr, nullptr, nullptr, N);
  // layer 2 (128 -> 128)
  k_gatherx<128><<<(N+3)/4, 256, 0, stream>>>((const uint2*)x1, offs, csr, eps2,
                                              (uint2*)hbuf, N);
  k_mlp<128,128,128,false><<<Npad/64, 256, 0, stream>>>(hbuf, wperm+24576, b2a, wperm+40960, b2b,
                                                        x1, nullptr, nullptr, nullptr, nullptr, N);
  // layer 3 (128 -> 64) + FC (64 -> 8)
  k_gatherx<128><<<(N+3)/4, 256, 0, stream>>>((const uint2*)x1, offs, csr, eps3,
                                              (uint2*)hbuf, N);
  k_mlp<128,64,64,true><<<Npad/64, 256, 0, stream>>>(hbuf, wperm+57344, b3a, wperm+65536, b3b,
                                                     nullptr, emb, wperm+69632, bfc, outp, N);
}